// Round 16
// baseline (169.001 us; speedup 1.0000x reference)
//
#include <hip/hip_runtime.h>
#include <math.h>

// ---------------- problem constants ----------------
#define BATCH   16
#define T_LEN   262144
#define NB      16          // biquad stages
#define L       64          // samples per chunk
#define GRP     64          // chunks per group (== wave width)
#define SUB     8           // chunks per sub-group (chain depth)
#define NSUB    512         // sub-groups per batch
#define NSUP    32          // super-groups per batch
#define NG      64          // groups (waves) per batch
#define NCHUNK  4096        // chunks per batch
#define XSTRIDE 68          // LDS audio row stride (64 + 4 pad)

#define DPI 3.14159265358979323846264338327950288

// ---------------- ws layout (floats) ----------------
#define OFF_COEF  0          // [16][96]
#define OFF_A64   1536       // [16][32][32]  A^64    (f32, f64-computed)
#define OFF_A512  17920      // [16][32][32]  A^512
#define OFF_A8K   34304      // [16][32][32]  A^8192
#define OFF_QEND  50688      // [16][512][32] zero-init sub-group totals
#define OFF_SARR  312832     // [16][512][32] sub-group start states
#define OFF_P     574976     // [16][64][32][64] chunk-final states, transposed
#define OFF_YZ    2672128    // [16][262144]  zero-state outputs (k1 -> k3)
#define OFF_W     6866432    // [16][32][64]  W[j][t] = (c^T A^t)_j  (f32 sims)
// total = 6,899,200 floats ~= 27.6 MB (ws is 268 MB)

// ---------------- stage coefficient math (f64) ----------------
__device__ inline void stage_coefs(int i, double fn, double gn, double qn,
                                   double& B0, double& B1, double& B2,
                                   double& A1, double& A2) {
    const double FS = 96000.0;
    double Q    = exp(log(0.5) + qn * (log(16.0) - log(0.5)));
    double gain = -24.0 + gn * 48.0;
    double lo, hi;
    if (i == 0)            { lo = 20.0;   hi = 500.0;   }
    else if (i == 15)      { lo = 5000.0; hi = 20000.0; }
    else if (i == 1 || i == 14) { lo = 50.0; hi = 16000.0; }
    else                   { lo = 100.0;  hi = 15000.0; }
    double fc    = exp(log(lo) + fn * (log(hi) - log(lo)));
    double w0    = 2.0 * DPI * fc / FS;
    double alpha = sin(w0) / (2.0 * Q);
    double c     = cos(w0);
    double b0, b1, b2, a0, a1, a2;
    if (i == 0) {
        b0 = (1.0 + c) * 0.5; b1 = -(1.0 + c); b2 = (1.0 + c) * 0.5;
        a0 = 1.0 + alpha; a1 = -2.0 * c; a2 = 1.0 - alpha;
    } else if (i == 15) {
        b0 = (1.0 - c) * 0.5; b1 = 1.0 - c; b2 = (1.0 - c) * 0.5;
        a0 = 1.0 + alpha; a1 = -2.0 * c; a2 = 1.0 - alpha;
    } else if (i == 1) {
        double A = pow(10.0, gain / 40.0), sA = sqrt(A);
        b0 = A * ((A + 1.0) - (A - 1.0) * c + 2.0 * sA * alpha);
        b1 = 2.0 * A * ((A - 1.0) - (A + 1.0) * c);
        b2 = A * ((A + 1.0) - (A - 1.0) * c - 2.0 * sA * alpha);
        a0 = (A + 1.0) + (A - 1.0) * c + 2.0 * sA * alpha;
        a1 = -2.0 * ((A - 1.0) + (A + 1.0) * c);
        a2 = (A + 1.0) + (A - 1.0) * c - 2.0 * sA * alpha;
    } else if (i == 14) {
        double A = pow(10.0, gain / 40.0), sA = sqrt(A);
        b0 = A * ((A + 1.0) + (A - 1.0) * c + 2.0 * sA * alpha);
        b1 = -2.0 * A * ((A - 1.0) + (A + 1.0) * c);
        b2 = A * ((A + 1.0) + (A - 1.0) * c - 2.0 * sA * alpha);
        a0 = (A + 1.0) - (A - 1.0) * c + 2.0 * sA * alpha;
        a1 = 2.0 * ((A - 1.0) - (A + 1.0) * c);
        a2 = (A + 1.0) - (A - 1.0) * c - 2.0 * sA * alpha;
    } else {
        double A = pow(10.0, gain / 40.0);
        b0 = 1.0 + alpha * A; b1 = -2.0 * c; b2 = 1.0 - alpha * A;
        a0 = 1.0 + alpha / A; a1 = -2.0 * c; a2 = 1.0 - alpha / A;
    }
    B0 = b0 / a0; B1 = b1 / a0; B2 = b2 / a0; A1 = a1 / a0; A2 = a2 / a0;
}

// ---------------- K0: coefs + A powers (f64) + W sims (f32) -----------------
// f64 REQUIRED for high powers (round-6 f32 chain overflowed).
// Threads 64..95 (wave 1) run 32 zero-input unit-state sims concurrently
// with the A build: lane j records W[j][k] = y(k) of state e_j -> W = c^T A^k.
__global__ __launch_bounds__(512) void k0_setup(const float* __restrict__ params,
                                                float* __restrict__ coefs,
                                                float* __restrict__ A64,
                                                float* __restrict__ A512,
                                                float* __restrict__ A8K,
                                                float* __restrict__ Wws) {
    int b = blockIdx.x;
    int t = threadIdx.x;
    __shared__ double cf[NB][5];
    __shared__ double M1[32 * 32];
    __shared__ double M2[32 * 32];

    if (t < NB) {
        double B0, B1, B2, A1, A2;
        stage_coefs(t, (double)params[b * 50 + t * 3 + 0],
                       (double)params[b * 50 + t * 3 + 1],
                       (double)params[b * 50 + t * 3 + 2], B0, B1, B2, A1, A2);
        float f0 = (float)B0, f1 = (float)B1, f2 = (float)B2, f3 = (float)A1, f4 = (float)A2;
        cf[t][0] = (double)f0; cf[t][1] = (double)f1; cf[t][2] = (double)f2;
        cf[t][3] = (double)f3; cf[t][4] = (double)f4;
        float* cp = coefs + b * 96 + t * 5;
        cp[0] = f0; cp[1] = f1; cp[2] = f2; cp[3] = f3; cp[4] = f4;
    }
    if (t == NB) {
        double indb = -60.0 + (double)params[b * 50 + 48] * 60.0;
        coefs[b * 96 + 80] = (float)pow(10.0, indb / 20.0);
    }
    if (t == NB + 1) {
        double outdb = -60.0 + (double)params[b * 50 + 49] * 60.0;
        coefs[b * 96 + 81] = (float)pow(10.0, outdb / 20.0);
    }
    __syncthreads();

    // A build (f64, t<32) and W sims (f32, t in [64,96)) run concurrently.
    if (t < 32) {
        double s1[NB], s2[NB];
#pragma unroll
        for (int i = 0; i < NB; i++) {
            s1[i] = (t == 2 * i) ? 1.0 : 0.0;
            s2[i] = (t == 2 * i + 1) ? 1.0 : 0.0;
        }
        double u = 0.0;
#pragma unroll
        for (int i = 0; i < NB; i++) {
            double y  = cf[i][0] * u + s1[i];
            double n1 = cf[i][1] * u - cf[i][3] * y + s2[i];
            double n2 = cf[i][2] * u - cf[i][4] * y;
            s1[i] = n1; s2[i] = n2; u = y;
        }
#pragma unroll
        for (int i = 0; i < NB; i++) {
            M1[(2 * i) * 32 + t]     = s1[i];
            M1[(2 * i + 1) * 32 + t] = s2[i];
        }
    } else if (t >= 64 && t < 96) {
        int j = t - 64;
        float fc0[NB], fc1[NB], fc2[NB], fc3[NB], fc4[NB];
#pragma unroll
        for (int i = 0; i < NB; i++) {
            fc0[i] = (float)cf[i][0]; fc1[i] = (float)cf[i][1];
            fc2[i] = (float)cf[i][2]; fc3[i] = (float)cf[i][3];
            fc4[i] = (float)cf[i][4];
        }
        float s1[NB], s2[NB];
#pragma unroll
        for (int i = 0; i < NB; i++) {
            s1[i] = (j == 2 * i) ? 1.f : 0.f;
            s2[i] = (j == 2 * i + 1) ? 1.f : 0.f;
        }
        float* wp = Wws + (size_t)b * 2048 + j * 64;
#pragma unroll 1
        for (int k = 0; k < 64; k++) {
            float u = 0.f;
#pragma unroll
            for (int i = 0; i < NB; i++) {
                float y  = fmaf(fc0[i], u, s1[i]);
                float n1 = fmaf(fc1[i], u, s2[i]); n1 = fmaf(-fc3[i], y, n1);
                float n2 = fc2[i] * u;             n2 = fmaf(-fc4[i], y, n2);
                s1[i] = n1; s2[i] = n2; u = y;
            }
            wp[k] = u;     // y(k) for state e_j = W[j][k]
        }
    }
    __syncthreads();

    // 13 squarings; save A^64 (sq=5), A^512 (sq=8), A^8192 (sq=12).
    int c  = t & 31;
    int r0 = t >> 5;           // rows r0 and r0+16
    double* src = M1;
    double* dst = M2;
    for (int sq = 0; sq < 13; sq++) {
        double acc0 = 0.0, acc1 = 0.0;
        for (int k = 0; k < 32; k++) {
            double bv = src[k * 32 + c];
            acc0 += src[r0 * 32 + k] * bv;
            acc1 += src[(r0 + 16) * 32 + k] * bv;
        }
        dst[r0 * 32 + c]        = acc0;
        dst[(r0 + 16) * 32 + c] = acc1;
        __syncthreads();
        { double* tmp = src; src = dst; dst = tmp; }
        float* out_m = (sq == 5) ? A64 : (sq == 8) ? A512 : (sq == 12) ? A8K : nullptr;
        if (out_m) {
            int i0 = r0 * 32 + c, i1 = (r0 + 16) * 32 + c;
            out_m[b * 1024 + i0] = (float)src[i0];
            out_m[b * 1024 + i1] = (float)src[i1];
        }
        __syncthreads();
    }
}

// ---------------- LDS-broadcast matvec step, 4 dual-half slots --------------
__device__ __forceinline__ void bc_step4(float* qldsw, int row, int cb,
                                         const float* ar,
                                         float p0, float p1, float p2, float p3,
                                         float& q0, float& q1, float& q2, float& q3) {
    qldsw[(cb + 0) * 32 + row] = q0;
    qldsw[(cb + 1) * 32 + row] = q1;
    qldsw[(cb + 2) * 32 + row] = q2;
    qldsw[(cb + 3) * 32 + row] = q3;
    const float* qb = qldsw + cb * 32;
    float a0 = p0, b0 = 0.f, a1 = p1, b1 = 0.f;
    float a2 = p2, b2 = 0.f, a3 = p3, b3 = 0.f;
#pragma unroll
    for (int t4 = 0; t4 < 8; t4++) {
        float4 v0 = *(const float4*)(qb + 0 * 32 + 4 * t4);
        float4 v1 = *(const float4*)(qb + 1 * 32 + 4 * t4);
        float4 v2 = *(const float4*)(qb + 2 * 32 + 4 * t4);
        float4 v3 = *(const float4*)(qb + 3 * 32 + 4 * t4);
        a0 = fmaf(ar[4 * t4 + 0], v0.x, a0); b0 = fmaf(ar[4 * t4 + 1], v0.y, b0);
        a0 = fmaf(ar[4 * t4 + 2], v0.z, a0); b0 = fmaf(ar[4 * t4 + 3], v0.w, b0);
        a1 = fmaf(ar[4 * t4 + 0], v1.x, a1); b1 = fmaf(ar[4 * t4 + 1], v1.y, b1);
        a1 = fmaf(ar[4 * t4 + 2], v1.z, a1); b1 = fmaf(ar[4 * t4 + 3], v1.w, b1);
        a2 = fmaf(ar[4 * t4 + 0], v2.x, a2); b2 = fmaf(ar[4 * t4 + 1], v2.y, b2);
        a2 = fmaf(ar[4 * t4 + 2], v2.z, a2); b2 = fmaf(ar[4 * t4 + 3], v2.w, b2);
        a3 = fmaf(ar[4 * t4 + 0], v3.x, a3); b3 = fmaf(ar[4 * t4 + 1], v3.y, b3);
        a3 = fmaf(ar[4 * t4 + 2], v3.z, a3); b3 = fmaf(ar[4 * t4 + 3], v3.w, b3);
    }
    q0 = a0 + b0; q1 = a1 + b1; q2 = a2 + b2; q3 = a3 + b3;
}

// readlane step (kept only for k2's tiny 32-step super scan)
__device__ __forceinline__ float mv_step_rl(const float* ar, float q, float addv) {
    int qi = __float_as_int(q);
    float qb[32];
#pragma unroll
    for (int t = 0; t < 32; t++)
        qb[t] = __int_as_float(__builtin_amdgcn_readlane(qi, t));
    float acc0 = addv, acc1 = 0.f;
#pragma unroll
    for (int t = 0; t < 32; t += 2) {
        acc0 = fmaf(ar[t], qb[t], acc0);
        acc1 = fmaf(ar[t + 1], qb[t + 1], acc1);
    }
    return acc0 + acc1;
}

__device__ __forceinline__ void load_row32(const float* base, int row, float* ar) {
    const float4* a4 = (const float4*)(base + row * 32);
#pragma unroll
    for (int j = 0; j < 8; j++) {
        float4 v = a4[j];
        ar[4 * j + 0] = v.x; ar[4 * j + 1] = v.y;
        ar[4 * j + 2] = v.z; ar[4 * j + 3] = v.w;
    }
}

// Coalesced stage: 16 KB wave footprint (contiguous global) -> LDS [chunk][68]
__device__ __forceinline__ void stage_audio(const float* __restrict__ gbase,
                                            float* __restrict__ xlds, int lane) {
    const float4* g4 = (const float4*)gbase;
    float4 v[16];
#pragma unroll
    for (int it = 0; it < 16; it++) v[it] = g4[it * 64 + lane];
#pragma unroll
    for (int it = 0; it < 16; it++) {
        int idx = it * 64 + lane;
        int ch = idx >> 4, q = idx & 15;
        *(float4*)&xlds[ch * XSTRIDE + q * 4] = v[it];
    }
}

// ---------------- K1: cascade (states + y_zero) + sub-group totals ----------
__global__ __launch_bounds__(64, 1) void k1_pass1(const float* __restrict__ audio,
                                                  const float* __restrict__ coefs,
                                                  const float* __restrict__ A64,
                                                  float* __restrict__ P,
                                                  float* __restrict__ Qend,
                                                  float* __restrict__ Yz) {
    int blk   = blockIdx.x;          // 0..1023
    int batch = blk >> 6;
    int grp   = blk & 63;
    int lane  = threadIdx.x;
    int row   = lane & 31;
    int half  = lane >> 5;

    __shared__ float xlds[GRP * XSTRIDE];   // audio in, y_zero out (in place)
    __shared__ float plds[GRP][33];
    __shared__ float qlds[8 * 32];

    stage_audio(audio + (size_t)batch * T_LEN + (size_t)grp * GRP * L, xlds, lane);
    __syncthreads();

    const float* cf = coefs + batch * 96;
    float c0[NB], c1[NB], c2[NB], c3[NB], c4[NB];
#pragma unroll
    for (int i = 0; i < NB; i++) {
        c0[i] = cf[i * 5 + 0]; c1[i] = cf[i * 5 + 1]; c2[i] = cf[i * 5 + 2];
        c3[i] = cf[i * 5 + 3]; c4[i] = cf[i * 5 + 4];
    }
    float ing = cf[80];

    float s1[NB], s2[NB];
#pragma unroll
    for (int i = 0; i < NB; i++) { s1[i] = 0.f; s2[i] = 0.f; }

    float* xrow = &xlds[lane * XSTRIDE];
#pragma unroll 1
    for (int tt = 0; tt < 16; tt++) {
        float4 xv = *(const float4*)&xrow[tt * 4];
        float xs[4] = {xv.x, xv.y, xv.z, xv.w};
        float ys[4];
#pragma unroll
        for (int j = 0; j < 4; j++) {
            float u = ing * xs[j];
#pragma unroll
            for (int i = 0; i < NB; i++) {
                float y  = fmaf(c0[i], u, s1[i]);
                float n1 = fmaf(c1[i], u, s2[i]); n1 = fmaf(-c3[i], y, n1);
                float n2 = c2[i] * u;             n2 = fmaf(-c4[i], y, n2);
                s1[i] = n1; s2[i] = n2; u = y;
            }
            ys[j] = u;                      // zero-state output (no outg)
        }
        float4 yv; yv.x = ys[0]; yv.y = ys[1]; yv.z = ys[2]; yv.w = ys[3];
        *(float4*)&xrow[tt * 4] = yv;       // y_zero overwrites consumed x
    }

    // P write: transposed layout P[grp][state][chunk] -> 32 coalesced stores
    {
        float* pb = P + ((size_t)(batch * NG + grp)) * 2048;
#pragma unroll
        for (int i = 0; i < NB; i++) {
            pb[(2 * i) * 64 + lane]     = s1[i];
            pb[(2 * i + 1) * 64 + lane] = s2[i];
        }
    }

#pragma unroll
    for (int i = 0; i < NB; i++) {
        plds[lane][2 * i]     = s1[i];
        plds[lane][2 * i + 1] = s2[i];
    }
    __syncthreads();

    // coalesced y_zero -> Yz (cross-lane transpose read; after the barrier)
    {
        float4* g4 = (float4*)(Yz + (size_t)batch * T_LEN + (size_t)grp * GRP * L);
#pragma unroll
        for (int it = 0; it < 16; it++) {
            int idx = it * 64 + lane;
            int ch = idx >> 4, q = idx & 15;
            g4[idx] = *(const float4*)&xlds[ch * XSTRIDE + q * 4];
        }
    }

    // 8 chains of depth 8, packed as 4 dual-half slots
    float ar[32];
    load_row32(A64 + batch * 1024, row, ar);
    int cb = half * 4;
    float q0 = plds[(cb + 0) * SUB][row];
    float q1 = plds[(cb + 1) * SUB][row];
    float q2 = plds[(cb + 2) * SUB][row];
    float q3 = plds[(cb + 3) * SUB][row];
#pragma unroll 1
    for (int j = 1; j < SUB; j++) {
        float p0 = plds[(cb + 0) * SUB + j][row];
        float p1 = plds[(cb + 1) * SUB + j][row];
        float p2 = plds[(cb + 2) * SUB + j][row];
        float p3 = plds[(cb + 3) * SUB + j][row];
        bc_step4(qlds, row, cb, ar, p0, p1, p2, p3, q0, q1, q2, q3);
    }
    {
        float* qe = Qend + ((size_t)(batch * NSUB + grp * 8 + cb)) * 32 + row;
        qe[0] = q0; qe[32] = q1; qe[64] = q2; qe[96] = q3;
    }
}

// ---------------- K2: full hierarchical combine, one block per batch --------
__global__ __launch_bounds__(256, 1) void k2_combine(const float* __restrict__ A512,
                                                     const float* __restrict__ A8K,
                                                     const float* __restrict__ Qend,
                                                     float* __restrict__ Sarr) {
    int batch = blockIdx.x;
    int tid   = threadIdx.x;
    int wave  = tid >> 6;
    int lane  = tid & 63;
    int row   = lane & 31;
    int half  = lane >> 5;
    int cb    = half * 4;

    __shared__ float qe[NSUB][32];          // 64 KB
    __shared__ float qs[NSUP][32];
    __shared__ float ss[NSUP][32];
    __shared__ float qlds[4][8 * 32];

    {
        const float4* src4 = (const float4*)(Qend + (size_t)batch * NSUB * 32);
        float4* dst4 = (float4*)&qe[0][0];
        for (int i = tid; i < NSUB * 32 / 4; i += 256) dst4[i] = src4[i];
    }
    float ar512[32];
    load_row32(A512 + batch * 1024, row, ar512);
    __syncthreads();

    int sbase = wave * 8 + cb;

    // C1: chains over 16 subs per sup
    {
        float q0 = qe[(sbase + 0) * 16][row];
        float q1 = qe[(sbase + 1) * 16][row];
        float q2 = qe[(sbase + 2) * 16][row];
        float q3 = qe[(sbase + 3) * 16][row];
#pragma unroll 1
        for (int j = 1; j < 16; j++) {
            float p0 = qe[(sbase + 0) * 16 + j][row];
            float p1 = qe[(sbase + 1) * 16 + j][row];
            float p2 = qe[(sbase + 2) * 16 + j][row];
            float p3 = qe[(sbase + 3) * 16 + j][row];
            bc_step4(qlds[wave], row, cb, ar512, p0, p1, p2, p3, q0, q1, q2, q3);
        }
        qs[sbase + 0][row] = q0; qs[sbase + 1][row] = q1;
        qs[sbase + 2][row] = q2; qs[sbase + 3][row] = q3;
    }
    __syncthreads();

    // C2: wave 0 scans 32 supers with A^8192
    if (wave == 0) {
        float ark[32];
        load_row32(A8K + batch * 1024, row, ark);
        float S = 0.f;
#pragma unroll 1
        for (int s = 0; s < NSUP; s++) {
            if (lane < 32) ss[s][row] = S;
            float addv = qs[s][row];
            S = mv_step_rl(ark, S, addv);
        }
    }
    __syncthreads();

    // C3: seeded sub-scans -> Sarr
    {
        float q0 = ss[sbase + 0][row];
        float q1 = ss[sbase + 1][row];
        float q2 = ss[sbase + 2][row];
        float q3 = ss[sbase + 3][row];
#pragma unroll 1
        for (int j = 0; j < 16; j++) {
            Sarr[((size_t)(batch * NSUB + (sbase + 0) * 16 + j)) * 32 + row] = q0;
            Sarr[((size_t)(batch * NSUB + (sbase + 1) * 16 + j)) * 32 + row] = q1;
            Sarr[((size_t)(batch * NSUB + (sbase + 2) * 16 + j)) * 32 + row] = q2;
            Sarr[((size_t)(batch * NSUB + (sbase + 3) * 16 + j)) * 32 + row] = q3;
            if (j < 15) {
                float p0 = qe[(sbase + 0) * 16 + j][row];
                float p1 = qe[(sbase + 1) * 16 + j][row];
                float p2 = qe[(sbase + 2) * 16 + j][row];
                float p3 = qe[(sbase + 3) * 16 + j][row];
                bc_step4(qlds[wave], row, cb, ar512, p0, p1, p2, p3, q0, q1, q2, q3);
            }
        }
    }
}

// ---------------- K3: superposition output: y = y_zero + W·s_start ----------
// NO cascade recurrence: seeded chains give s_start per chunk, then a fully
// ILP-parallel rank-1 loop (2048 independent FMAs, 64 accumulators) applies
// the state-response W. This is the discriminating test for whether the
// unattributed k1/k3 stall is attached to the serial recurrence.
__global__ __launch_bounds__(64, 1) void k3_pass2(const float* __restrict__ Yz,
                                                  const float* __restrict__ coefs,
                                                  const float* __restrict__ A64,
                                                  const float* __restrict__ Wws,
                                                  const float* __restrict__ P,
                                                  const float* __restrict__ Sarr,
                                                  float* __restrict__ out) {
    int blk   = blockIdx.x;
    int batch = blk >> 6;
    int grp   = blk & 63;
    int lane  = threadIdx.x;
    int row   = lane & 31;
    int half  = lane >> 5;
    int cb    = half * 4;

    __shared__ float xlds[GRP * XSTRIDE];   // y_zero in, y out (in place)
    __shared__ float plds[GRP][33];
    __shared__ float qlds[8 * 32];
    __shared__ __align__(16) float wlds[2048];   // W[j][t]

    stage_audio(Yz + (size_t)batch * T_LEN + (size_t)grp * GRP * L, xlds, lane);

    // W stage: 8 KB coalesced
    {
        const float* wsrc = Wws + (size_t)batch * 2048;
#pragma unroll
        for (int it = 0; it < 32; it++)
            wlds[it * 64 + lane] = wsrc[it * 64 + lane];
    }

    // coalesced P load (transposed layout) -> LDS
    {
        const float* pb = P + ((size_t)(batch * NG + grp)) * 2048;
        float pv[32];
#pragma unroll
        for (int s = 0; s < 32; s++) pv[s] = pb[s * 64 + lane];
#pragma unroll
        for (int s = 0; s < 32; s++) plds[lane][s] = pv[s];
    }
    __syncthreads();

    // 8 seeded chains (dual-half); overwrite plds[ch][row] with start states
    {
        float ar[32];
        load_row32(A64 + batch * 1024, row, ar);
        const float* sp = Sarr + ((size_t)(batch * NSUB + grp * 8 + cb)) * 32 + row;
        float q0 = sp[0], q1 = sp[32], q2 = sp[64], q3 = sp[96];
#pragma unroll 1
        for (int j = 0; j < SUB; j++) {
            float p0 = plds[(cb + 0) * SUB + j][row];
            float p1 = plds[(cb + 1) * SUB + j][row];
            float p2 = plds[(cb + 2) * SUB + j][row];
            float p3 = plds[(cb + 3) * SUB + j][row];
            plds[(cb + 0) * SUB + j][row] = q0;
            plds[(cb + 1) * SUB + j][row] = q1;
            plds[(cb + 2) * SUB + j][row] = q2;
            plds[(cb + 3) * SUB + j][row] = q3;
            if (j < SUB - 1)
                bc_step4(qlds, row, cb, ar, p0, p1, p2, p3, q0, q1, q2, q3);
        }
    }
    __syncthreads();

    float outg = coefs[batch * 96 + 81];

    // s_start for this lane's chunk
    float sst[32];
#pragma unroll
    for (int s = 0; s < 32; s++) sst[s] = plds[lane][s];

    // y accumulators init = y_zero
    float* xrow = &xlds[lane * XSTRIDE];
    float y[64];
#pragma unroll
    for (int tt = 0; tt < 16; tt++) {
        float4 v = *(const float4*)&xrow[tt * 4];
        y[4 * tt + 0] = v.x; y[4 * tt + 1] = v.y;
        y[4 * tt + 2] = v.z; y[4 * tt + 3] = v.w;
    }

    // rank-1 updates: y[t] += W[j][t] * sst[j]  (W broadcast, all independent)
#pragma unroll 1
    for (int j = 0; j < 32; j++) {
        float sj = sst[j];
        const float* wr = &wlds[j * 64];
#pragma unroll
        for (int t4 = 0; t4 < 16; t4++) {
            float4 w = *(const float4*)&wr[4 * t4];
            y[4 * t4 + 0] = fmaf(w.x, sj, y[4 * t4 + 0]);
            y[4 * t4 + 1] = fmaf(w.y, sj, y[4 * t4 + 1]);
            y[4 * t4 + 2] = fmaf(w.z, sj, y[4 * t4 + 2]);
            y[4 * t4 + 3] = fmaf(w.w, sj, y[4 * t4 + 3]);
        }
    }

    // scale + write back in place, then coalesced out
#pragma unroll
    for (int tt = 0; tt < 16; tt++) {
        float4 v;
        v.x = outg * y[4 * tt + 0]; v.y = outg * y[4 * tt + 1];
        v.z = outg * y[4 * tt + 2]; v.w = outg * y[4 * tt + 3];
        *(float4*)&xrow[tt * 4] = v;
    }
    __syncthreads();

    {
        float4* g4 = (float4*)(out + (size_t)batch * T_LEN + (size_t)grp * GRP * L);
#pragma unroll
        for (int it = 0; it < 16; it++) {
            int idx = it * 64 + lane;
            int ch = idx >> 4, q = idx & 15;
            g4[idx] = *(const float4*)&xlds[ch * XSTRIDE + q * 4];
        }
    }
}

// ---------------- launcher ----------------
extern "C" void kernel_launch(void* const* d_in, const int* in_sizes, int n_in,
                              void* d_out, int out_size, void* d_ws, size_t ws_size,
                              hipStream_t stream) {
    const float* audio  = (const float*)d_in[0];
    const float* params = (const float*)d_in[1];
    float* out = (float*)d_out;
    float* ws  = (float*)d_ws;

    float* coefs = ws + OFF_COEF;
    float* A64   = ws + OFF_A64;
    float* A512  = ws + OFF_A512;
    float* A8K   = ws + OFF_A8K;
    float* Qend  = ws + OFF_QEND;
    float* Sarr  = ws + OFF_SARR;
    float* P     = ws + OFF_P;
    float* Yz    = ws + OFF_YZ;
    float* Wws   = ws + OFF_W;

    k0_setup<<<BATCH, 512, 0, stream>>>(params, coefs, A64, A512, A8K, Wws);
    k1_pass1<<<BATCH * NG, 64, 0, stream>>>(audio, coefs, A64, P, Qend, Yz);
    k2_combine<<<BATCH, 256, 0, stream>>>(A512, A8K, Qend, Sarr);
    k3_pass2<<<BATCH * NG, 64, 0, stream>>>(Yz, coefs, A64, Wws, P, Sarr, out);
}

// Round 17
// 151.974 us; speedup vs baseline: 1.1120x; 1.1120x over previous
//
#include <hip/hip_runtime.h>
#include <math.h>

// ---------------- problem constants ----------------
#define BATCH   16
#define T_LEN   262144
#define NB      16          // biquad stages
#define L       64          // samples per chunk
#define GRP     64          // chunks per group (== wave width)
#define SUB     16          // chunks per sub-group
#define CHAINS  4           // sub-groups per wave
#define NSUB    256         // sub-groups per batch
#define NSUP    16          // super-groups per batch
#define NG      64          // groups (waves) per batch
#define NCHUNK  4096        // chunks per batch
#define XSTRIDE 68          // LDS audio row stride (64 + 4 pad -> 4-way banks)

#define DPI 3.14159265358979323846264338327950288

// ---------------- ws layout (floats) ----------------
#define OFF_COEF  0          // [16][96]
#define OFF_A64   1536       // [16][32][32]  A^64    (f32, f64-computed)
#define OFF_A1K   17920      // [16][32][32]  A^1024
#define OFF_A16K  34304      // [16][32][32]  A^16384
#define OFF_QEND  50688      // [16][256][32] zero-init sub-group totals
#define OFF_SARR  181760     // [16][256][32] sub-group start states
#define OFF_P     312832     // [16][64][32][64] chunk-final states, transposed
// total = 312832 + 16*64*2048 = 3,409,984 floats ~= 13.6 MB

// ---------------- stage coefficient math (f64) ----------------
__device__ inline void stage_coefs(int i, double fn, double gn, double qn,
                                   double& B0, double& B1, double& B2,
                                   double& A1, double& A2) {
    const double FS = 96000.0;
    double Q    = exp(log(0.5) + qn * (log(16.0) - log(0.5)));
    double gain = -24.0 + gn * 48.0;
    double lo, hi;
    if (i == 0)            { lo = 20.0;   hi = 500.0;   }
    else if (i == 15)      { lo = 5000.0; hi = 20000.0; }
    else if (i == 1 || i == 14) { lo = 50.0; hi = 16000.0; }
    else                   { lo = 100.0;  hi = 15000.0; }
    double fc    = exp(log(lo) + fn * (log(hi) - log(lo)));
    double w0    = 2.0 * DPI * fc / FS;
    double alpha = sin(w0) / (2.0 * Q);
    double c     = cos(w0);
    double b0, b1, b2, a0, a1, a2;
    if (i == 0) {
        b0 = (1.0 + c) * 0.5; b1 = -(1.0 + c); b2 = (1.0 + c) * 0.5;
        a0 = 1.0 + alpha; a1 = -2.0 * c; a2 = 1.0 - alpha;
    } else if (i == 15) {
        b0 = (1.0 - c) * 0.5; b1 = 1.0 - c; b2 = (1.0 - c) * 0.5;
        a0 = 1.0 + alpha; a1 = -2.0 * c; a2 = 1.0 - alpha;
    } else if (i == 1) {
        double A = pow(10.0, gain / 40.0), sA = sqrt(A);
        b0 = A * ((A + 1.0) - (A - 1.0) * c + 2.0 * sA * alpha);
        b1 = 2.0 * A * ((A - 1.0) - (A + 1.0) * c);
        b2 = A * ((A + 1.0) - (A - 1.0) * c - 2.0 * sA * alpha);
        a0 = (A + 1.0) + (A - 1.0) * c + 2.0 * sA * alpha;
        a1 = -2.0 * ((A - 1.0) + (A + 1.0) * c);
        a2 = (A + 1.0) + (A - 1.0) * c - 2.0 * sA * alpha;
    } else if (i == 14) {
        double A = pow(10.0, gain / 40.0), sA = sqrt(A);
        b0 = A * ((A + 1.0) + (A - 1.0) * c + 2.0 * sA * alpha);
        b1 = -2.0 * A * ((A - 1.0) + (A + 1.0) * c);
        b2 = A * ((A + 1.0) + (A - 1.0) * c - 2.0 * sA * alpha);
        a0 = (A + 1.0) - (A - 1.0) * c + 2.0 * sA * alpha;
        a1 = 2.0 * ((A - 1.0) - (A + 1.0) * c);
        a2 = (A + 1.0) - (A - 1.0) * c - 2.0 * sA * alpha;
    } else {
        double A = pow(10.0, gain / 40.0);
        b0 = 1.0 + alpha * A; b1 = -2.0 * c; b2 = 1.0 - alpha * A;
        a0 = 1.0 + alpha / A; a1 = -2.0 * c; a2 = 1.0 - alpha / A;
    }
    B0 = b0 / a0; B1 = b1 / a0; B2 = b2 / a0; A1 = a1 / a0; A2 = a2 / a0;
}

// ---------------- K0: coefs + A^64 / A^1024 / A^16384 (f64) -----------------
// f64 REQUIRED: intermediate powers of the non-normal cascade matrix
// transiently exceed f32 range (round-6 f32 chain -> Inf -> NaN).
__global__ __launch_bounds__(256) void k0_setup(const float* __restrict__ params,
                                                float* __restrict__ coefs,
                                                float* __restrict__ A64,
                                                float* __restrict__ A1K,
                                                float* __restrict__ A16K) {
    int b = blockIdx.x;
    int t = threadIdx.x;
    __shared__ double cf[NB][5];
    __shared__ double M1[32 * 32];
    __shared__ double M2[32 * 32];

    if (t < NB) {
        double B0, B1, B2, A1, A2;
        stage_coefs(t, (double)params[b * 50 + t * 3 + 0],
                       (double)params[b * 50 + t * 3 + 1],
                       (double)params[b * 50 + t * 3 + 2], B0, B1, B2, A1, A2);
        float f0 = (float)B0, f1 = (float)B1, f2 = (float)B2, f3 = (float)A1, f4 = (float)A2;
        cf[t][0] = (double)f0; cf[t][1] = (double)f1; cf[t][2] = (double)f2;
        cf[t][3] = (double)f3; cf[t][4] = (double)f4;
        float* cp = coefs + b * 96 + t * 5;
        cp[0] = f0; cp[1] = f1; cp[2] = f2; cp[3] = f3; cp[4] = f4;
    }
    if (t == NB) {
        double indb = -60.0 + (double)params[b * 50 + 48] * 60.0;
        coefs[b * 96 + 80] = (float)pow(10.0, indb / 20.0);
    }
    if (t == NB + 1) {
        double outdb = -60.0 + (double)params[b * 50 + 49] * 60.0;
        coefs[b * 96 + 81] = (float)pow(10.0, outdb / 20.0);
    }
    __syncthreads();

    if (t < 32) {
        double s1[NB], s2[NB];
#pragma unroll
        for (int i = 0; i < NB; i++) {
            s1[i] = (t == 2 * i) ? 1.0 : 0.0;
            s2[i] = (t == 2 * i + 1) ? 1.0 : 0.0;
        }
        double u = 0.0;
#pragma unroll
        for (int i = 0; i < NB; i++) {
            double y  = cf[i][0] * u + s1[i];
            double n1 = cf[i][1] * u - cf[i][3] * y + s2[i];
            double n2 = cf[i][2] * u - cf[i][4] * y;
            s1[i] = n1; s2[i] = n2; u = y;
        }
#pragma unroll
        for (int i = 0; i < NB; i++) {
            M1[(2 * i) * 32 + t]     = s1[i];
            M1[(2 * i + 1) * 32 + t] = s2[i];
        }
    }
    __syncthreads();

    // 14 squarings; save A^64 (sq=5), A^1024 (sq=9), A^16384 (sq=13).
    // thread t: column c=t&31, rows r0+{0,8,16,24}; conflict-free (m136).
    int c  = t & 31;
    int r0 = t >> 5;
    double* src = M1;
    double* dst = M2;
    for (int sq = 0; sq < 14; sq++) {
        double acc[4] = {0.0, 0.0, 0.0, 0.0};
        for (int k = 0; k < 32; k++) {
            double bv = src[k * 32 + c];
#pragma unroll
            for (int e = 0; e < 4; e++)
                acc[e] += src[(e * 8 + r0) * 32 + k] * bv;
        }
#pragma unroll
        for (int e = 0; e < 4; e++) dst[(e * 8 + r0) * 32 + c] = acc[e];
        __syncthreads();
        { double* tmp = src; src = dst; dst = tmp; }
        float* out_m = (sq == 5) ? A64 : (sq == 9) ? A1K : (sq == 13) ? A16K : nullptr;
        if (out_m) {
#pragma unroll
            for (int e = 0; e < 4; e++) {
                int idx = (e * 8 + r0) * 32 + c;
                out_m[b * 1024 + idx] = (float)src[idx];
            }
        }
        __syncthreads();
    }
}

// ---------------- readlane matvec step (grouped broadcasts) -----------------
// All 32 lane-broadcasts first, then the FMA chain. q broadcast via
// v_readlane (no LDS, no lgkmcnt); dual accumulators.
__device__ __forceinline__ float mv_step_rl(const float* ar, float q, float addv) {
    int qi = __float_as_int(q);
    float qb[32];
#pragma unroll
    for (int t = 0; t < 32; t++)
        qb[t] = __int_as_float(__builtin_amdgcn_readlane(qi, t));
    float acc0 = addv, acc1 = 0.f;
#pragma unroll
    for (int t = 0; t < 32; t += 2) {
        acc0 = fmaf(ar[t], qb[t], acc0);
        acc1 = fmaf(ar[t + 1], qb[t + 1], acc1);
    }
    return acc0 + acc1;
}

__device__ __forceinline__ void load_row32(const float* base, int row, float* ar) {
    const float4* a4 = (const float4*)(base + row * 32);
#pragma unroll
    for (int j = 0; j < 8; j++) {
        float4 v = a4[j];
        ar[4 * j + 0] = v.x; ar[4 * j + 1] = v.y;
        ar[4 * j + 2] = v.z; ar[4 * j + 3] = v.w;
    }
}

// Coalesced audio stage: the wave's 16 KB (64 chunks x 256 B, contiguous in
// global) -> 16 fully-coalesced float4 loads -> LDS [chunk][68].
__device__ __forceinline__ void stage_audio(const float* __restrict__ gbase,
                                            float* __restrict__ xlds, int lane) {
    const float4* g4 = (const float4*)gbase;
    float4 v[16];
#pragma unroll
    for (int it = 0; it < 16; it++) v[it] = g4[it * 64 + lane];
#pragma unroll
    for (int it = 0; it < 16; it++) {
        int idx = it * 64 + lane;
        int ch = idx >> 4, q = idx & 15;
        *(float4*)&xlds[ch * XSTRIDE + q * 4] = v[it];
    }
}

// ---------------- K1: zero-init chunk states + sub-group totals -------------
__global__ __launch_bounds__(64, 1) void k1_pass1(const float* __restrict__ audio,
                                                  const float* __restrict__ coefs,
                                                  const float* __restrict__ A64,
                                                  float* __restrict__ P,
                                                  float* __restrict__ Qend) {
    int blk   = blockIdx.x;          // 0..1023
    int batch = blk >> 6;
    int grp   = blk & 63;
    int lane  = threadIdx.x;
    int row   = lane & 31;

    __shared__ float xlds[GRP * XSTRIDE];   // 17.4 KB
    __shared__ float plds[GRP][33];         //  8.4 KB

    stage_audio(audio + (size_t)batch * T_LEN + (size_t)grp * GRP * L, xlds, lane);
    __syncthreads();

    const float* cf = coefs + batch * 96;
    float c0[NB], c1[NB], c2[NB], c3[NB], c4[NB];
#pragma unroll
    for (int i = 0; i < NB; i++) {
        c0[i] = cf[i * 5 + 0]; c1[i] = cf[i * 5 + 1]; c2[i] = cf[i * 5 + 2];
        c3[i] = cf[i * 5 + 3]; c4[i] = cf[i * 5 + 4];
    }
    float ing = cf[80];

    float s1[NB], s2[NB];
#pragma unroll
    for (int i = 0; i < NB; i++) { s1[i] = 0.f; s2[i] = 0.f; }

    float* xrow = &xlds[lane * XSTRIDE];
#pragma unroll 1
    for (int tt = 0; tt < 16; tt++) {
        float4 xv = *(const float4*)&xrow[tt * 4];   // ds_read_b128
        float xs[4] = {xv.x, xv.y, xv.z, xv.w};
#pragma unroll
        for (int j = 0; j < 4; j++) {
            float u = ing * xs[j];
#pragma unroll
            for (int i = 0; i < NB; i++) {
                float y  = fmaf(c0[i], u, s1[i]);
                float n1 = fmaf(c1[i], u, s2[i]); n1 = fmaf(-c3[i], y, n1);
                float n2 = c2[i] * u;             n2 = fmaf(-c4[i], y, n2);
                s1[i] = n1; s2[i] = n2; u = y;
            }
        }
    }

    // P write: transposed layout P[grp][state][chunk] -> 32 coalesced stores
    {
        float* pb = P + ((size_t)(batch * NG + grp)) * 2048;
#pragma unroll
        for (int i = 0; i < NB; i++) {
            pb[(2 * i) * 64 + lane]     = s1[i];
            pb[(2 * i + 1) * 64 + lane] = s2[i];
        }
    }

#pragma unroll
    for (int i = 0; i < NB; i++) {
        plds[lane][2 * i]     = s1[i];
        plds[lane][2 * i + 1] = s2[i];
    }
    __syncthreads();

    // 4 independent 16-step chains (readlane matvec, A^64)
    float ar[32];
    load_row32(A64 + batch * 1024, row, ar);
    float q0 = 0.f, q1 = 0.f, q2 = 0.f, q3 = 0.f;
#pragma unroll 1
    for (int j = 0; j < SUB; j++) {
        float p0 = plds[0 * SUB + j][row];
        float p1 = plds[1 * SUB + j][row];
        float p2 = plds[2 * SUB + j][row];
        float p3 = plds[3 * SUB + j][row];
        q0 = mv_step_rl(ar, q0, p0);
        q1 = mv_step_rl(ar, q1, p1);
        q2 = mv_step_rl(ar, q2, p2);
        q3 = mv_step_rl(ar, q3, p3);
    }
    if (lane < 32) {
        float* qe = Qend + ((size_t)(batch * NSUB + grp * CHAINS)) * 32 + row;
        qe[0] = q0; qe[32] = q1; qe[64] = q2; qe[96] = q3;
    }
}

// ---------------- K2: full hierarchical combine, one block per batch --------
__global__ __launch_bounds__(256, 1) void k2_combine(const float* __restrict__ A1K,
                                                     const float* __restrict__ A16K,
                                                     const float* __restrict__ Qend,
                                                     float* __restrict__ Sarr) {
    int batch = blockIdx.x;
    int tid   = threadIdx.x;
    int wave  = tid >> 6;
    int lane  = tid & 63;
    int row   = lane & 31;

    __shared__ float qe[NSUB][32];   // 32 KB
    __shared__ float qs[NSUP][32];
    __shared__ float ss[NSUP][32];

    {
        const float4* src4 = (const float4*)(Qend + (size_t)batch * NSUB * 32);
        float4* dst4 = (float4*)&qe[0][0];
        for (int i = tid; i < NSUB * 32 / 4; i += 256) dst4[i] = src4[i];
    }
    float ar1k[32];
    load_row32(A1K + batch * 1024, row, ar1k);
    __syncthreads();

    // C1: wave w -> sups w*4..w*4+3 (4-ILP readlane chains, A^1024)
    int s0i = wave * 4;
    {
        float q0 = 0.f, q1 = 0.f, q2 = 0.f, q3 = 0.f;
#pragma unroll 1
        for (int j = 0; j < 16; j++) {
            float p0 = qe[(s0i + 0) * 16 + j][row];
            float p1 = qe[(s0i + 1) * 16 + j][row];
            float p2 = qe[(s0i + 2) * 16 + j][row];
            float p3 = qe[(s0i + 3) * 16 + j][row];
            q0 = mv_step_rl(ar1k, q0, p0);
            q1 = mv_step_rl(ar1k, q1, p1);
            q2 = mv_step_rl(ar1k, q2, p2);
            q3 = mv_step_rl(ar1k, q3, p3);
        }
        if (lane < 32) {
            qs[s0i + 0][row] = q0; qs[s0i + 1][row] = q1;
            qs[s0i + 2][row] = q2; qs[s0i + 3][row] = q3;
        }
    }
    __syncthreads();

    // C2: wave 0 scans 16 supers with A^16384 (readlane)
    if (wave == 0) {
        float ark[32];
        load_row32(A16K + batch * 1024, row, ark);
        float S = 0.f;
#pragma unroll 1
        for (int s = 0; s < NSUP; s++) {
            if (lane < 32) ss[s][row] = S;
            float addv = qs[s][row];
            S = mv_step_rl(ark, S, addv);
        }
    }
    __syncthreads();

    // C3: seeded sub-scans -> Sarr
    {
        float q0 = ss[s0i + 0][row];
        float q1 = ss[s0i + 1][row];
        float q2 = ss[s0i + 2][row];
        float q3 = ss[s0i + 3][row];
#pragma unroll 1
        for (int j = 0; j < 16; j++) {
            if (lane < 32) {
                Sarr[((size_t)(batch * NSUB + (s0i + 0) * 16 + j)) * 32 + row] = q0;
                Sarr[((size_t)(batch * NSUB + (s0i + 1) * 16 + j)) * 32 + row] = q1;
                Sarr[((size_t)(batch * NSUB + (s0i + 2) * 16 + j)) * 32 + row] = q2;
                Sarr[((size_t)(batch * NSUB + (s0i + 3) * 16 + j)) * 32 + row] = q3;
            }
            float p0 = qe[(s0i + 0) * 16 + j][row];
            float p1 = qe[(s0i + 1) * 16 + j][row];
            float p2 = qe[(s0i + 2) * 16 + j][row];
            float p3 = qe[(s0i + 3) * 16 + j][row];
            q0 = mv_step_rl(ar1k, q0, p0);
            q1 = mv_step_rl(ar1k, q1, p1);
            q2 = mv_step_rl(ar1k, q2, p2);
            q3 = mv_step_rl(ar1k, q3, p3);
        }
    }
}

// ---------------- K3: corrected-init re-run, write output ----------------
__global__ __launch_bounds__(64, 1) void k3_pass2(const float* __restrict__ audio,
                                                  const float* __restrict__ coefs,
                                                  const float* __restrict__ A64,
                                                  const float* __restrict__ P,
                                                  const float* __restrict__ Sarr,
                                                  float* __restrict__ out) {
    int blk   = blockIdx.x;
    int batch = blk >> 6;
    int grp   = blk & 63;
    int lane  = threadIdx.x;
    int row   = lane & 31;

    __shared__ float xlds[GRP * XSTRIDE];   // audio in, y out (in place)
    __shared__ float plds[GRP][33];

    stage_audio(audio + (size_t)batch * T_LEN + (size_t)grp * GRP * L, xlds, lane);

    // coalesced P load (transposed layout) -> LDS
    {
        const float* pb = P + ((size_t)(batch * NG + grp)) * 2048;
        float pv[32];
#pragma unroll
        for (int s = 0; s < 32; s++) pv[s] = pb[s * 64 + lane];
#pragma unroll
        for (int s = 0; s < 32; s++) plds[lane][s] = pv[s];
    }
    __syncthreads();

    // 4 seeded readlane chains; overwrite plds[k][row] with chunk-k start state
    {
        float ar[32];
        load_row32(A64 + batch * 1024, row, ar);
        const float* sp = Sarr + ((size_t)(batch * NSUB + grp * CHAINS)) * 32 + row;
        float q0 = sp[0], q1 = sp[32], q2 = sp[64], q3 = sp[96];
#pragma unroll 1
        for (int j = 0; j < SUB; j++) {
            float p0 = plds[0 * SUB + j][row];
            float p1 = plds[1 * SUB + j][row];
            float p2 = plds[2 * SUB + j][row];
            float p3 = plds[3 * SUB + j][row];
            if (lane < 32) {
                plds[0 * SUB + j][row] = q0;
                plds[1 * SUB + j][row] = q1;
                plds[2 * SUB + j][row] = q2;
                plds[3 * SUB + j][row] = q3;
            }
            q0 = mv_step_rl(ar, q0, p0);
            q1 = mv_step_rl(ar, q1, p1);
            q2 = mv_step_rl(ar, q2, p2);
            q3 = mv_step_rl(ar, q3, p3);
        }
    }
    __syncthreads();

    const float* cf = coefs + batch * 96;
    float c0[NB], c1[NB], c2[NB], c3[NB], c4[NB];
#pragma unroll
    for (int i = 0; i < NB; i++) {
        c0[i] = cf[i * 5 + 0]; c1[i] = cf[i * 5 + 1]; c2[i] = cf[i * 5 + 2];
        c3[i] = cf[i * 5 + 3]; c4[i] = cf[i * 5 + 4];
    }
    float ing  = cf[80];
    float outg = cf[81];

    float s1[NB], s2[NB];
#pragma unroll
    for (int i = 0; i < NB; i++) {
        s1[i] = plds[lane][2 * i];
        s2[i] = plds[lane][2 * i + 1];
    }

    float* xrow = &xlds[lane * XSTRIDE];
#pragma unroll 1
    for (int tt = 0; tt < 16; tt++) {
        float4 xv = *(const float4*)&xrow[tt * 4];
        float xs[4] = {xv.x, xv.y, xv.z, xv.w};
        float ys[4];
#pragma unroll
        for (int j = 0; j < 4; j++) {
            float u = ing * xs[j];
#pragma unroll
            for (int i = 0; i < NB; i++) {
                float y  = fmaf(c0[i], u, s1[i]);
                float n1 = fmaf(c1[i], u, s2[i]); n1 = fmaf(-c3[i], y, n1);
                float n2 = c2[i] * u;             n2 = fmaf(-c4[i], y, n2);
                s1[i] = n1; s2[i] = n2; u = y;
            }
            ys[j] = outg * u;
        }
        float4 yv; yv.x = ys[0]; yv.y = ys[1]; yv.z = ys[2]; yv.w = ys[3];
        *(float4*)&xrow[tt * 4] = yv;   // in-place: y overwrites consumed x
    }
    __syncthreads();

    // coalesced LDS -> global out
    {
        float4* g4 = (float4*)(out + (size_t)batch * T_LEN + (size_t)grp * GRP * L);
#pragma unroll
        for (int it = 0; it < 16; it++) {
            int idx = it * 64 + lane;
            int ch = idx >> 4, q = idx & 15;
            g4[it * 64 + lane] = *(const float4*)&xlds[ch * XSTRIDE + q * 4];
        }
    }
}

// ---------------- launcher ----------------
extern "C" void kernel_launch(void* const* d_in, const int* in_sizes, int n_in,
                              void* d_out, int out_size, void* d_ws, size_t ws_size,
                              hipStream_t stream) {
    const float* audio  = (const float*)d_in[0];
    const float* params = (const float*)d_in[1];
    float* out = (float*)d_out;
    float* ws  = (float*)d_ws;

    float* coefs = ws + OFF_COEF;
    float* A64   = ws + OFF_A64;
    float* A1K   = ws + OFF_A1K;
    float* A16K  = ws + OFF_A16K;
    float* Qend  = ws + OFF_QEND;
    float* Sarr  = ws + OFF_SARR;
    float* P     = ws + OFF_P;

    k0_setup<<<BATCH, 256, 0, stream>>>(params, coefs, A64, A1K, A16K);
    k1_pass1<<<BATCH * NG, 64, 0, stream>>>(audio, coefs, A64, P, Qend);
    k2_combine<<<BATCH, 256, 0, stream>>>(A1K, A16K, Qend, Sarr);
    k3_pass2<<<BATCH * NG, 64, 0, stream>>>(audio, coefs, A64, P, Sarr, out);
}